// Round 1
// baseline (503.645 us; speedup 1.0000x reference)
//
#include <hip/hip_runtime.h>
#include <hip/hip_bf16.h>

// Problem: BasicBlock (binary conv block), N=32, C=256, H=W=56, fp32 in/out.
// Binary structure: conv inputs are sign() in {-1,0,1}; weights scale[o]*sign(w).
// => compute conv(sign, sign) with bf16 MFMA (exact integer arithmetic),
//    fold scale into BN constants in fp32 epilogue.

#define NB   32
#define CCH  256
#define HH   56
#define WW   56
#define PIMG 3136      // 56*56
#define MTOT 100352    // 32*3136
#define HP   58
#define WP   58
#define SPIX 3364      // 58*58

typedef __attribute__((ext_vector_type(8))) short short8;
typedef __attribute__((ext_vector_type(4))) float floatx4;

// ---------------- kernel 1: transpose + binarize x into padded NHWC bf16 ----
// spad[n][hp][wp][c], hp/wp in [0,58), pad sites = 0
__global__ void transpose_sign(const float* __restrict__ x,
                               const float* __restrict__ b11,
                               unsigned short* __restrict__ spad) {
    const int hp = blockIdx.x;          // 0..57
    const int cb = blockIdx.y;          // 0..3 (64 channels each)
    const int n  = blockIdx.z;          // 0..31
    const int t  = threadIdx.x;         // 256
    __shared__ float tile[64 * 57];

    const bool border_h = (hp == 0) || (hp == 57);
    if (!border_h) {
        const int h = hp - 1;
        for (int it = 0; it < 14; ++it) {           // 64 rows * 56 cols = 3584
            int lin = t + it * 256;
            int row = lin / 56;
            int col = lin - row * 56;
            int cg  = cb * 64 + row;
            float v = x[((size_t)(n * CCH + cg)) * PIMG + h * WW + col] + b11[cg];
            tile[row * 57 + col] = (v > 0.f) ? 1.f : ((v < 0.f) ? -1.f : 0.f);
        }
    }
    __syncthreads();
    for (int it = 0; it < 15; ++it) {               // 58 wp * 64 c = 3712
        int lin = t + it * 256;
        if (lin >= 58 * 64) break;
        int wp = lin >> 6;
        int c  = lin & 63;
        float s = 0.f;
        if (!border_h && wp >= 1 && wp <= 56) s = tile[c * 57 + (wp - 1)];
        unsigned short us = (s > 0.f) ? 0x3F80 : ((s < 0.f) ? 0xBF80 : 0);
        spad[((size_t)(n * SPIX + hp * WP + wp)) * CCH + cb * 64 + c] = us;
    }
}

// ---------------- kernel 2: weight binarize + BN fold ----------------------
// wq3t[r9][o][c] (r9 = kh*3+kw), wq1t[o][c]
__global__ void prep_w(const float* __restrict__ w3, const float* __restrict__ w1,
                       const float* __restrict__ g1, const float* __restrict__ be1,
                       const float* __restrict__ m1, const float* __restrict__ v1,
                       const float* __restrict__ g2, const float* __restrict__ be2,
                       const float* __restrict__ m2, const float* __restrict__ v2,
                       unsigned short* __restrict__ wq3t, unsigned short* __restrict__ wq1t,
                       float* __restrict__ k2s, float* __restrict__ k2b,
                       float* __restrict__ k3s, float* __restrict__ k3b) {
    const int o = blockIdx.x;   // 0..511
    const int t = threadIdx.x;  // 256
    __shared__ float red[256];
    if (o < 256) {
        const float* wp = w3 + (size_t)o * 2304;
        float s = 0.f;
        for (int i = t; i < 2304; i += 256) s += fabsf(wp[i]);
        red[t] = s; __syncthreads();
        for (int k = 128; k > 0; k >>= 1) { if (t < k) red[t] += red[t + k]; __syncthreads(); }
        float scale = red[0] * (1.0f / 2304.0f);
        for (int i = t; i < 2304; i += 256) {
            int c = i / 9; int r = i - c * 9;
            float w = wp[i];
            wq3t[((size_t)(r * 256 + o)) * 256 + c] =
                (w > 0.f) ? 0x3F80 : ((w < 0.f) ? 0xBF80 : 0);
        }
        if (t == 0) {
            float inv = g1[o] * rsqrtf(v1[o] + 1e-5f);
            k2s[o] = scale * inv;
            k2b[o] = be1[o] - m1[o] * inv;
        }
    } else {
        const int o1 = o - 256;
        const float* wp = w1 + (size_t)o1 * 256;
        float w = wp[t];
        red[t] = fabsf(w); __syncthreads();
        for (int k = 128; k > 0; k >>= 1) { if (t < k) red[t] += red[t + k]; __syncthreads(); }
        float scale = red[0] * (1.0f / 256.0f);
        wq1t[(size_t)o1 * 256 + t] = (w > 0.f) ? 0x3F80 : ((w < 0.f) ? 0xBF80 : 0);
        if (t == 0) {
            float inv = g2[o1] * rsqrtf(v2[o1] + 1e-5f);
            k3s[o1] = scale * inv;
            k3b[o1] = be2[o1] - m2[o1] * inv;
        }
    }
}

// ---------------- kernel 3: 3x3 binary conv as implicit GEMM ---------------
// C[m][o] over K = 9 offsets x 256 c. 128x128 tile, 4 waves, 16x16x32 bf16 MFMA.
// Epilogue: out1 = prelu(x + bn(scale*acc) + b12, a1) + b13 -> d_out (fp32 NCHW)
//           sgn  = sign(out1 + b21) -> bf16 NHWC [m][o]
__global__ __launch_bounds__(256, 2) void gemm3x3(
    const unsigned short* __restrict__ spad, const unsigned short* __restrict__ wq3t,
    const float* __restrict__ x,
    const float* __restrict__ k2s, const float* __restrict__ k2b,
    const float* __restrict__ b12, const float* __restrict__ b13,
    const float* __restrict__ b21, const float* __restrict__ a1,
    float* __restrict__ out1, unsigned short* __restrict__ sgn) {
    __shared__ __align__(16) unsigned short As[128 * 72];  // [m][c] +8 pad
    __shared__ __align__(16) unsigned short Bs[128 * 72];  // [o][c] +8 pad
    const int t    = threadIdx.x;
    const int mb   = blockIdx.x;    // 784
    const int nb   = blockIdx.y;    // 2
    const int lane = t & 63;
    const int wid  = t >> 6;
    const int wm   = wid & 1;       // wave m-pos (2x2 wave grid over 128x128)
    const int wn   = wid >> 1;
    const int quad = lane >> 4;
    const int l16  = lane & 15;

    floatx4 acc[4][4] = {};

    // staging: 8 threads/row x 32 rows/round x 4 rounds; 16B per thread
    const int srow = t >> 3;          // 0..31
    const int scol = (t & 7) * 8;     // element col, 16B granules
    int abase[4];
    for (int r = 0; r < 4; ++r) {
        int row = srow + r * 32;
        int m = mb * 128 + row;
        int n_img = m / PIMG;
        int p = m - n_img * PIMG;
        int h = p / WW;
        int w = p - h * WW;
        abase[r] = n_img * SPIX + h * WP + w;   // +kh*58+kw per offset (pad shift)
    }

    for (int r9 = 0; r9 < 9; ++r9) {
        const int kh = r9 / 3, kw = r9 - kh * 3;
        const int shift = kh * WP + kw;
        for (int cb = 0; cb < 4; ++cb) {
            for (int r = 0; r < 4; ++r) {
                int row = srow + r * 32;
                const int4* gp = (const int4*)(spad +
                    (size_t)(abase[r] + shift) * CCH + cb * 64 + scol);
                *(int4*)(&As[row * 72 + scol]) = *gp;
            }
            for (int r = 0; r < 4; ++r) {
                int row = srow + r * 32;
                const int4* gp = (const int4*)(wq3t +
                    (size_t)(r9 * 256 + nb * 128 + row) * 256 + cb * 64 + scol);
                *(int4*)(&Bs[row * 72 + scol]) = *gp;
            }
            __syncthreads();
            for (int ks = 0; ks < 2; ++ks) {
                short8 af[4], bf[4];
                for (int i = 0; i < 4; ++i)
                    af[i] = *(const short8*)(&As[(wm * 64 + i * 16 + l16) * 72 + ks * 32 + quad * 8]);
                for (int j = 0; j < 4; ++j)
                    bf[j] = *(const short8*)(&Bs[(wn * 64 + j * 16 + l16) * 72 + ks * 32 + quad * 8]);
                for (int i = 0; i < 4; ++i)
                    for (int j = 0; j < 4; ++j)
                        acc[i][j] = __builtin_amdgcn_mfma_f32_16x16x32_bf16(
                            af[i], bf[j], acc[i][j], 0, 0, 0);
            }
            __syncthreads();
        }
    }

    // epilogue
    for (int j = 0; j < 4; ++j) {
        const int o = nb * 128 + wn * 64 + j * 16 + l16;
        const float sc = k2s[o], bt = k2b[o];
        const float v12 = b12[o], v13 = b13[o], v21 = b21[o], va = a1[o];
        for (int i = 0; i < 4; ++i) {
            const int m0 = mb * 128 + wm * 64 + i * 16 + quad * 4;
            const int n_img = m0 / PIMG;
            const int p0 = m0 - n_img * PIMG;
            const size_t goff = (size_t)(n_img * CCH + o) * PIMG + p0;
            const float4 xv = *(const float4*)(x + goff);
            float rr[4] = {xv.x, xv.y, xv.z, xv.w};
            float res[4];
            for (int r = 0; r < 4; ++r) {
                float v  = acc[i][j][r] * sc + bt + rr[r];
                float tt = v + v12;
                float o1 = ((tt > 0.f) ? tt : va * tt) + v13;
                res[r] = o1;
                float s = o1 + v21;
                sgn[(size_t)(m0 + r) * 256 + o] =
                    (s > 0.f) ? 0x3F80 : ((s < 0.f) ? 0xBF80 : 0);
            }
            float4 ov; ov.x = res[0]; ov.y = res[1]; ov.z = res[2]; ov.w = res[3];
            *(float4*)(out1 + goff) = ov;
        }
    }
}

// ---------------- kernel 4: 1x1 binary conv GEMM + final epilogue ----------
// reads out1 from `out` (d_out), writes final result in place (same thread).
__global__ __launch_bounds__(256, 2) void gemm1x1(
    const unsigned short* __restrict__ sgnA, const unsigned short* __restrict__ wq1t,
    const float* __restrict__ k3s, const float* __restrict__ k3b,
    const float* __restrict__ b22, const float* __restrict__ b23,
    const float* __restrict__ a2,
    float* __restrict__ out) {
    __shared__ __align__(16) unsigned short As[128 * 72];
    __shared__ __align__(16) unsigned short Bs[128 * 72];
    const int t    = threadIdx.x;
    const int mb   = blockIdx.x;
    const int nb   = blockIdx.y;
    const int lane = t & 63;
    const int wid  = t >> 6;
    const int wm   = wid & 1;
    const int wn   = wid >> 1;
    const int quad = lane >> 4;
    const int l16  = lane & 15;

    floatx4 acc[4][4] = {};
    const int srow = t >> 3;
    const int scol = (t & 7) * 8;

    for (int cb = 0; cb < 4; ++cb) {
        for (int r = 0; r < 4; ++r) {
            int row = srow + r * 32;
            const int4* gp = (const int4*)(sgnA +
                (size_t)(mb * 128 + row) * 256 + cb * 64 + scol);
            *(int4*)(&As[row * 72 + scol]) = *gp;
        }
        for (int r = 0; r < 4; ++r) {
            int row = srow + r * 32;
            const int4* gp = (const int4*)(wq1t +
                (size_t)(nb * 128 + row) * 256 + cb * 64 + scol);
            *(int4*)(&Bs[row * 72 + scol]) = *gp;
        }
        __syncthreads();
        for (int ks = 0; ks < 2; ++ks) {
            short8 af[4], bf[4];
            for (int i = 0; i < 4; ++i)
                af[i] = *(const short8*)(&As[(wm * 64 + i * 16 + l16) * 72 + ks * 32 + quad * 8]);
            for (int j = 0; j < 4; ++j)
                bf[j] = *(const short8*)(&Bs[(wn * 64 + j * 16 + l16) * 72 + ks * 32 + quad * 8]);
            for (int i = 0; i < 4; ++i)
                for (int j = 0; j < 4; ++j)
                    acc[i][j] = __builtin_amdgcn_mfma_f32_16x16x32_bf16(
                        af[i], bf[j], acc[i][j], 0, 0, 0);
        }
        __syncthreads();
    }

    for (int j = 0; j < 4; ++j) {
        const int o = nb * 128 + wn * 64 + j * 16 + l16;
        const float sc = k3s[o], bt = k3b[o];
        const float v22 = b22[o], v23 = b23[o], va = a2[o];
        for (int i = 0; i < 4; ++i) {
            const int m0 = mb * 128 + wm * 64 + i * 16 + quad * 4;
            const int n_img = m0 / PIMG;
            const int p0 = m0 - n_img * PIMG;
            const size_t goff = (size_t)(n_img * CCH + o) * PIMG + p0;
            const float4 o1v = *(const float4*)(out + goff);
            float rr[4] = {o1v.x, o1v.y, o1v.z, o1v.w};
            float res[4];
            for (int r = 0; r < 4; ++r) {
                float v  = acc[i][j][r] * sc + bt + rr[r];
                float tt = v + v22;
                res[r] = ((tt > 0.f) ? tt : va * tt) + v23;
            }
            float4 ov; ov.x = res[0]; ov.y = res[1]; ov.z = res[2]; ov.w = res[3];
            *(float4*)(out + goff) = ov;
        }
    }
}

// ---------------- launch ---------------------------------------------------
extern "C" void kernel_launch(void* const* d_in, const int* in_sizes, int n_in,
                              void* d_out, int out_size, void* d_ws, size_t ws_size,
                              hipStream_t stream) {
    const float* x   = (const float*)d_in[0];
    const float* w3  = (const float*)d_in[1];
    const float* w1  = (const float*)d_in[2];
    const float* b11 = (const float*)d_in[3];
    const float* b12 = (const float*)d_in[4];
    const float* b13 = (const float*)d_in[5];
    const float* b21 = (const float*)d_in[6];
    const float* b22 = (const float*)d_in[7];
    const float* b23 = (const float*)d_in[8];
    const float* g1  = (const float*)d_in[9];
    const float* be1 = (const float*)d_in[10];
    const float* m1  = (const float*)d_in[11];
    const float* v1  = (const float*)d_in[12];
    const float* g2  = (const float*)d_in[13];
    const float* be2 = (const float*)d_in[14];
    const float* m2  = (const float*)d_in[15];
    const float* v2  = (const float*)d_in[16];
    const float* a1  = (const float*)d_in[17];
    const float* a2  = (const float*)d_in[18];
    float* out = (float*)d_out;

    char* ws = (char*)d_ws;
    // spad:  32*58*58*256 bf16 = 55,115,776 B
    // sgn:   100352*256 bf16   = 51,380,224 B
    // wq3t:  9*256*256 bf16    =  1,179,648 B
    // wq1t:  256*256 bf16      =    131,072 B
    // consts: 4*256 f32
    unsigned short* spad = (unsigned short*)(ws);
    unsigned short* sgn  = (unsigned short*)(ws + 55115776);
    unsigned short* wq3t = (unsigned short*)(ws + 106496000);
    unsigned short* wq1t = (unsigned short*)(ws + 107675648);
    float* k2s = (float*)(ws + 107806720);
    float* k2b = k2s + 256;
    float* k3s = k2s + 512;
    float* k3b = k2s + 768;

    transpose_sign<<<dim3(58, 4, 32), 256, 0, stream>>>(x, b11, spad);
    prep_w<<<512, 256, 0, stream>>>(w3, w1, g1, be1, m1, v1, g2, be2, m2, v2,
                                    wq3t, wq1t, k2s, k2b, k3s, k3b);
    gemm3x3<<<dim3(784, 2), 256, 0, stream>>>(spad, wq3t, x, k2s, k2b,
                                              b12, b13, b21, a1, out, sgn);
    gemm1x1<<<dim3(784, 2), 256, 0, stream>>>(sgn, wq1t, k3s, k3b,
                                              b22, b23, a2, out);
}